// Round 1
// baseline (324.508 us; speedup 1.0000x reference)
//
#include <hip/hip_runtime.h>

#define NC 8192
#define NT 4096
#define NLAGS 103
#define WS_STRIDE 104
#define XBASE (NC*NLAGS)

// ---------------- Kernel 1: per-channel cross-correlation ----------------
// Persistent blocks: CPB channels each, double-buffered d1 in LDS, d2 via
// per-lane global loads. Lag base -1 (waves cover lags -1..110, valid 0..102)
// makes the left zero-pad 52 (== 0 mod 4) so d1 staging is aligned b128.
// Padded LDS: +4 dwords per 32 -> lane stride 36 (36l % 32 = 4l % 32: every
// 8 lanes' b128 reads cover all 32 banks).
#define PADL 52
#define PADR 60
#define P32(x) ((x) + (((x) >> 5) << 2))   // logical -> physical dword index
#define D1PA 4736          // phys span of 4208 logical (4732) rounded to x16
#define SMEMF (2*D1PA)     // 37.9 KB -> 3 blocks/CU (VGPR-bound anyway)
#define CPB 4
#define LPW 28
#define REDS 29            // reduction row stride (odd: conflict-free)

__global__ __launch_bounds__(256, 3)
void xcorr_kernel(const float* __restrict__ g1, const float* __restrict__ g2,
                  float* __restrict__ ws) {
    __shared__ __align__(16) float smem[SMEMF];
    const int tid  = threadIdx.x;
    const int wv   = tid >> 6;
    const int lane = tid & 63;
    const int c0   = blockIdx.x * CPB;

    // zero the pads of both buffers once (right pad is never clobbered;
    // left pad is re-zeroed after each reduction)
    #pragma unroll
    for (int bb = 0; bb < 2; ++bb) {
        float* buf = smem + bb * D1PA;
        if (tid < PADL) buf[P32(tid)] = 0.f;
        if (tid < PADR) buf[P32(PADL + NT + tid)] = 0.f;
    }
    // stage d1(c0) into buf0 — data starts at logical 52 (%4==0): aligned b128
    {
        const float4* r = (const float4*)(g1 + (size_t)c0 * NT);
        #pragma unroll
        for (int i = 0; i < 4; ++i) {
            float4 v = r[tid + 256*i];
            int x = PADL + 4*(tid + 256*i);
            *(float4*)&smem[P32(x)] = v;
        }
    }
    __syncthreads();

    #pragma unroll 1
    for (int ci = 0; ci < CPB; ++ci) {
        const int c = c0 + ci;
        float* cur  = smem + (ci & 1) * D1PA;
        float* nxtb = smem + ((ci & 1) ^ 1) * D1PA;
        const float* g2c = g2 + (size_t)c * NT;

        // issue next channel's d1 loads now; LDS write happens post-compute.
        // nxtb is dead this epoch (prev reduction finished before last barrier).
        float4 nx0, nx1, nx2, nx3;
        const bool hasnext = (ci + 1 < CPB);
        if (hasnext) {
            const float4* r = (const float4*)(g1 + (size_t)(c + 1) * NT);
            nx0 = r[tid]; nx1 = r[tid + 256]; nx2 = r[tid + 512]; nx3 = r[tid + 768];
        }

        float acc[LPW];
        #pragma unroll
        for (int l = 0; l < LPW; ++l) acc[l] = 0.f;

        // acc[l] = R[28*wv - 1 + l]; K-chunk 32 per lane, 2 iters cover NT
        #pragma unroll 1
        for (int it = 0; it < 2; ++it) {
            const int k0 = it*2048 + lane*32;
            float b[32];                       // d2: lane-private, from global
            #pragma unroll
            for (int t = 0; t < 8; ++t) {
                float4 v = *(const float4*)(g2c + k0 + 4*t);
                b[4*t]=v.x; b[4*t+1]=v.y; b[4*t+2]=v.z; b[4*t+3]=v.w;
            }
            float w[60];                       // d1 window: 28 lags + 32 k
            const int wb = k0 + 28*wv;         // logical = k + L + 1, %4==0
            #pragma unroll
            for (int t = 0; t < 15; ++t) {
                float4 v = *(const float4*)&cur[P32(wb + 4*t)];
                w[4*t]=v.x; w[4*t+1]=v.y; w[4*t+2]=v.z; w[4*t+3]=v.w;
            }
            #pragma unroll
            for (int j = 0; j < 32; ++j)
                #pragma unroll
                for (int l = 0; l < LPW; ++l)
                    acc[l] = fmaf(w[l+j], b[j], acc[l]);
        }

        // write prefetched d1 into the other buffer (disjoint from cur)
        if (hasnext) {
            int x = PADL + 4*tid;
            *(float4*)&nxtb[P32(x)]        = nx0;
            *(float4*)&nxtb[P32(x + 1024)] = nx1;
            *(float4*)&nxtb[P32(x + 2048)] = nx2;
            *(float4*)&nxtb[P32(x + 3072)] = nx3;
        }
        __syncthreads();   // cur reads + nxtb staging complete

        // cross-lane reduction in the now-dead cur buffer
        #pragma unroll
        for (int l = 0; l < LPW; ++l) acc[l] += __shfl_down(acc[l], 32);
        float* red = cur + wv * (32*REDS);     // wave3 top = 3711 < 4736
        if (lane < 32) {
            #pragma unroll
            for (int l = 0; l < LPW; ++l) red[lane*REDS + l] = acc[l];
        }
        // same-wave DS ops complete in order: no barrier needed
        if (lane < LPW) {
            float sum = 0.f;
            #pragma unroll
            for (int r = 0; r < 32; ++r) sum += red[r*REDS + lane];
            const int L = 28*wv - 1 + lane;
            if (L >= 0 && L < NLAGS) ws[(size_t)c * WS_STRIDE + L] = sum;
        }
        if (tid < PADL) cur[P32(tid)] = 0.f;   // restore left pad (wave0, after reads)
        __syncthreads();
    }
}

// -------- Kernel 2: moving average across channels + pick max|R| --------
#define TS 112   // tile stride (16*7: rows alias 2-way = free)
__global__ __launch_bounds__(256, 4)
void ma_pick_kernel(const float* __restrict__ ws, float* __restrict__ out) {
    __shared__ float tile[52*TS];
    __shared__ float matile[32*TS];
    const int tid = threadIdx.x;
    const int c0  = blockIdx.x * 32;

    for (int i = tid; i < 52*TS; i += 256) {
        int r   = i / TS;
        int col = i - r*TS;
        int g   = c0 - 10 + r;
        float v = 0.f;
        if (g >= 0 && g < NC && col < NLAGS) v = ws[(size_t)g*WS_STRIDE + col];
        tile[i] = v;
    }
    __syncthreads();

    {   // rolling 20-channel window sum; thread = one lag, 16 channels
        const int l = tid & 127;
        const int h = tid >> 7;
        if (l < NLAGS) {
            const int cc0 = h * 16;
            float s = 0.f;
            #pragma unroll
            for (int r = 0; r < 20; ++r) s += tile[(cc0 + r)*TS + l];
            #pragma unroll 1
            for (int cc = cc0; cc < cc0 + 16; ++cc) {
                float ma = s / 20.0f;
                matile[cc*TS + l] = ma;
                out[(size_t)(c0 + cc)*NLAGS + l] = ma;   // coalesced across l
                s += tile[(cc + 20)*TS + l] - tile[cc*TS + l];
            }
        }
    }
    __syncthreads();

    // per-channel argmax|R| (first-index tie-break), max, min
    const int wv = tid >> 6, lane = tid & 63;
    #pragma unroll 1
    for (int s8 = 0; s8 < 8; ++s8) {
        const int cc = wv*8 + s8;
        float v1 = matile[cc*TS + lane];
        float a1 = fabsf(v1);
        int   i1 = lane;
        float vmx = v1, vmn = v1;
        if (lane < NLAGS - 64) {                 // second element: l = lane+64
            float v2 = matile[cc*TS + 64 + lane];
            float a2 = fabsf(v2);
            vmx = fmaxf(vmx, v2); vmn = fminf(vmn, v2);
            if (a2 > a1) { a1 = a2; i1 = 64 + lane; v1 = v2; }
        }
        #pragma unroll
        for (int d = 32; d >= 1; d >>= 1) {
            float oa  = __shfl_xor(a1, d);
            int   oi  = __shfl_xor(i1, d);
            float ov  = __shfl_xor(v1, d);
            float omx = __shfl_xor(vmx, d);
            float omn = __shfl_xor(vmn, d);
            vmx = fmaxf(vmx, omx);
            vmn = fminf(vmn, omn);
            if (oa > a1 || (oa == a1 && oi < i1)) { a1 = oa; i1 = oi; v1 = ov; }
        }
        if (lane == 0) {
            const int ch = c0 + cc;
            out[XBASE + ch]        = v1;                         // vmain
            out[XBASE + NC + ch]   = (v1 >= 0.f) ? vmn : vmx;    // vside
            out[XBASE + 2*NC + ch] = (float)(i1 - 51) * 0.01f;   // tmax
        }
    }
}

extern "C" void kernel_launch(void* const* d_in, const int* in_sizes, int n_in,
                              void* d_out, int out_size, void* d_ws, size_t ws_size,
                              hipStream_t stream) {
    const float* g1 = (const float*)d_in[0];
    const float* g2 = (const float*)d_in[1];
    float* out = (float*)d_out;
    float* ws  = (float*)d_ws;   // 8192*104*4 = 3.4 MB scratch

    hipLaunchKernelGGL(xcorr_kernel, dim3(NC/CPB), dim3(256), 0, stream, g1, g2, ws);
    hipLaunchKernelGGL(ma_pick_kernel, dim3(NC/32), dim3(256), 0, stream, ws, out);
}